// Round 9
// baseline (605.876 us; speedup 1.0000x reference)
//
#include <hip/hip_runtime.h>
#include <stdint.h>

// VectorQuantize on MI355X (gfx950) — bf16x3 MFMA distance-GEMM + argmin.
// Round 9: BM=256 x BN=128, wave 64x64 (acc[4][4]), X3/E3 ring (144KB) +
// e2-in-LDS, register frag-prefetch one step ahead so next-step ds_reads
// interleave with current MFMA burst (breaks the read/MFMA convoy of r8).
// d_out: [0..N*DIM) quantized (fp32), [N*DIM..+N) ind (fp32), loss, perplexity.

#define N_VEC 16384
#define M_CODES 8192
#define DIM 256
#define BETA 0.25f

#define NSLICE 4
#define SLICE_CODES 2048
#define BM 256
#define BN 128
#define NPART 8                  // NSLICE * 2 col halves

#define XSLOT 32768              // xh 16K | xl 16K   (256 rows x 64B)
#define ESLOT 16384              // eh 8K  | el 8K    (128 rows x 64B)
#define EBASE (3 * XSLOT)                    // 98304
#define E2OFF (EBASE + 3 * ESLOT)            // 147456
#define LDS_TOTAL (E2OFF + SLICE_CODES * 4)  // 155648 = 152 KiB
#define NSTEPS 128               // 16 ct x 8 kc

typedef __attribute__((ext_vector_type(4))) float f32x4;
typedef __attribute__((ext_vector_type(8))) __bf16 bf16x8;

__device__ __forceinline__ void gll16(const void* g, const void* lds_p) {
    __builtin_amdgcn_global_load_lds(
        (const __attribute__((address_space(1))) uint32_t*)(uintptr_t)g,
        (__attribute__((address_space(3))) uint32_t*)(uint32_t)(uintptr_t)lds_p,
        16, 0, 0);
}
#define SB0() __builtin_amdgcn_sched_barrier(0)

__device__ __forceinline__ ushort f2bf(float f) {
    uint32_t u = __float_as_uint(f);
    return (ushort)((u + 0x7FFFu + ((u >> 16) & 1u)) >> 16);  // RNE
}
__device__ __forceinline__ float bf2f(ushort h) {
    return __uint_as_float(((uint32_t)h) << 16);
}

// ---- fused: split fp32 -> bf16 hi/lo for x and e, e2, zero counts/loss ----
__global__ __launch_bounds__(256) void prep_kernel(
    const float* __restrict__ x, const float* __restrict__ emb,
    ushort* __restrict__ xh, ushort* __restrict__ xl,
    ushort* __restrict__ eh, ushort* __restrict__ el,
    float* __restrict__ e2, unsigned* __restrict__ counts,
    float* __restrict__ loss_acc) {
    if (blockIdx.x < 8) {
        int4 z = {0, 0, 0, 0};
        ((int4*)counts)[blockIdx.x * 256 + threadIdx.x] = z;
        if (blockIdx.x == 0 && threadIdx.x == 0) *loss_acc = 0.0f;
    }
    const int wave = threadIdx.x >> 6;
    const int lane = threadIdx.x & 63;
    const int row = blockIdx.x * 4 + wave;

    const float* src;
    ushort* ph;
    ushort* pl;
    bool is_e;
    int er = row - N_VEC;
    if (row < N_VEC) {
        src = x + (size_t)row * DIM;
        ph = xh + (size_t)row * DIM;
        pl = xl + (size_t)row * DIM;
        is_e = false;
    } else {
        src = emb + (size_t)er * DIM;
        ph = eh + (size_t)er * DIM;
        pl = el + (size_t)er * DIM;
        is_e = true;
    }
    float4 v = *(const float4*)(src + lane * 4);
    ushort h0 = f2bf(v.x), h1 = f2bf(v.y), h2 = f2bf(v.z), h3 = f2bf(v.w);
    ushort l0 = f2bf(v.x - bf2f(h0)), l1 = f2bf(v.y - bf2f(h1));
    ushort l2 = f2bf(v.z - bf2f(h2)), l3 = f2bf(v.w - bf2f(h3));
    *(ushort4*)(ph + lane * 4) = make_ushort4(h0, h1, h2, h3);
    *(ushort4*)(pl + lane * 4) = make_ushort4(l0, l1, l2, l3);
    if (is_e) {
        float s = v.x * v.x + v.y * v.y + v.z * v.z + v.w * v.w;
        #pragma unroll
        for (int off = 32; off; off >>= 1) s += __shfl_xor(s, off);
        if (lane == 0) e2[er] = s;
    }
}

// ------ main: bf16x3 MFMA distance GEMM, reg-prefetch pipeline, argmin ----
__global__ __launch_bounds__(512, 1) void vq_mfma_kernel(
    const ushort* __restrict__ xh, const ushort* __restrict__ xl,
    const ushort* __restrict__ eh, const ushort* __restrict__ el,
    const float* __restrict__ e2g, unsigned long long* __restrict__ partials) {
    extern __shared__ char lds[];

    const int t = threadIdx.x;
    const int lane = t & 63;
    const int wv = t >> 6;          // 0..7
    const int lane15 = lane & 15;
    const int l16 = lane >> 4;      // 0..3

    // rt-major mapping: XCD = bid%8 = rt%8 -> slice-siblings co-XCD
    const int rt = blockIdx.x & 63;
    const int slice = blockIdx.x >> 6;   // 0..3
    const int row0 = rt * BM;
    const int cslice0 = slice * SLICE_CODES;

    const int wr0 = (wv & 3) * 64;   // wave row quadrant 0..192
    const int wch = wv >> 2;         // wave col half (64 codes)

    // ---- fragment LDS byte bases (swizzle term is f-independent)
    const int swz = ((l16 ^ (lane15 >> 1)) & 3) << 4;
    const int byteA0 = (wr0 + lane15) * 64 + swz;
    const int byteB0 = (wch * 64 + lane15) * 64 + swz;

    // ---- staging: linear LDS dest, inverse-swizzled global source
    const int sX0 = wv * 128 + lane;
    const int sX1 = sX0 + 64;
    const int rX0 = sX0 >> 2, rX1 = sX1 >> 2;
    const int cX0 = ((sX0 & 3) ^ ((sX0 >> 3) & 3)) << 3;
    const int cX1 = ((sX1 & 3) ^ ((sX1 >> 3) & 3)) << 3;
    const int sE = wv * 64 + lane;
    const int rE = sE >> 2;
    const int cE = ((sE & 3) ^ ((sE >> 3) & 3)) << 3;

    const ushort* pxh_a = xh + (size_t)(row0 + rX0) * DIM + cX0;
    const ushort* pxh_b = xh + (size_t)(row0 + rX1) * DIM + cX1;
    const ushort* pxl_a = xl + (size_t)(row0 + rX0) * DIM + cX0;
    const ushort* pxl_b = xl + (size_t)(row0 + rX1) * DIM + cX1;
    const ushort* peh = eh + (size_t)(cslice0 + rE) * DIM + cE;
    const ushort* pel = el + (size_t)(cslice0 + rE) * DIM + cE;

    // ---- preload e2 slice into LDS; syncthreads drains vmcnt FIFO
    float* e2s = (float*)(lds + E2OFF);
    #pragma unroll
    for (int i = 0; i < 4; ++i) e2s[i * 512 + t] = e2g[cslice0 + i * 512 + t];
    __syncthreads();

    auto stage_X = [&](int slotOff, int s) {   // 4 gll
        char* b = lds + slotOff + wv * 2048;
        const int xo = (s & 7) * 32;
        gll16(pxh_a + xo, b);
        gll16(pxh_b + xo, b + 1024);
        gll16(pxl_a + xo, b + 16384);
        gll16(pxl_b + xo, b + 16384 + 1024);
    };
    auto stage_E = [&](int slotOff, int s) {   // 2 gll
        char* b = lds + slotOff + wv * 1024;
        const size_t eo = ((size_t)(s >> 3) << 15) + (s & 7) * 32;
        gll16(peh + eo, b);
        gll16(pel + eo, b + 8192);
    };

#define PREFETCH(XO, EO, AH, AL, BH, BL) do {                          \
    const char* lA_ = lds + (XO);                                      \
    const char* lB_ = lds + (EO);                                      \
    _Pragma("unroll") for (int f_ = 0; f_ < 4; ++f_) {                 \
        AH[f_] = *(const bf16x8*)(lA_ + byteA0 + f_ * 1024);           \
        AL[f_] = *(const bf16x8*)(lA_ + 16384 + byteA0 + f_ * 1024);   \
        BH[f_] = *(const bf16x8*)(lB_ + byteB0 + f_ * 1024);           \
        BL[f_] = *(const bf16x8*)(lB_ + 8192 + byteB0 + f_ * 1024);    \
    } } while (0)

#define MFMA3(AH, AL, BH, BL) do {                                               \
    _Pragma("unroll") for (int fi_ = 0; fi_ < 4; ++fi_)                          \
    _Pragma("unroll") for (int fj_ = 0; fj_ < 4; ++fj_)                          \
        acc[fi_][fj_] = __builtin_amdgcn_mfma_f32_16x16x32_bf16(                 \
            AH[fi_], BH[fj_], acc[fi_][fj_], 0, 0, 0);                           \
    _Pragma("unroll") for (int fi_ = 0; fi_ < 4; ++fi_)                          \
    _Pragma("unroll") for (int fj_ = 0; fj_ < 4; ++fj_)                          \
        acc[fi_][fj_] = __builtin_amdgcn_mfma_f32_16x16x32_bf16(                 \
            AH[fi_], BL[fj_], acc[fi_][fj_], 0, 0, 0);                           \
    _Pragma("unroll") for (int fi_ = 0; fi_ < 4; ++fi_)                          \
    _Pragma("unroll") for (int fj_ = 0; fj_ < 4; ++fj_)                          \
        acc[fi_][fj_] = __builtin_amdgcn_mfma_f32_16x16x32_bf16(                 \
            AL[fi_], BH[fj_], acc[fi_][fj_], 0, 0, 0);                           \
    } while (0)

#define EPILOGUE(CT) do {                                                        \
    const int clb_ = (CT) * BN + wch * 64 + lane15;                              \
    _Pragma("unroll") for (int fj_ = 0; fj_ < 4; ++fj_) {                        \
        const float e2v_ = e2s[clb_ + fj_ * 16];                                 \
        const int c_ = cslice0 + clb_ + fj_ * 16;                                \
        _Pragma("unroll") for (int fi_ = 0; fi_ < 4; ++fi_)                      \
        _Pragma("unroll") for (int r_ = 0; r_ < 4; ++r_) {                       \
            float sc_ = e2v_ - 2.0f * acc[fi_][fj_][r_];                         \
            const int sl_ = fi_ * 4 + r_;                                        \
            if (sc_ < best[sl_]) { best[sl_] = sc_; bidx[sl_] = c_; }            \
        }                                                                        \
    }                                                                            \
    _Pragma("unroll") for (int fi_ = 0; fi_ < 4; ++fi_)                          \
    _Pragma("unroll") for (int fj_ = 0; fj_ < 4; ++fj_)                          \
        acc[fi_][fj_] = (f32x4){0.f, 0.f, 0.f, 0.f};                             \
    } while (0)

// One pipeline step: frags(s) already in CUR regs; stage(s+2); prefetch(s+1)
// into NXT regs, interleaved by the scheduler with the 48-MFMA burst.
#define STEP(SVAL, CAH, CAL, CBH, CBL, NAH, NAL, NBH, NBL) do {                  \
    const int s_ = (SVAL);                                                       \
    asm volatile("s_waitcnt vmcnt(0) lgkmcnt(0)" ::: "memory");                  \
    SB0();                                                                       \
    __builtin_amdgcn_s_barrier();                                                \
    if (s_ + 2 < NSTEPS) { stage_X(xs2, s_ + 2); stage_E(es2, s_ + 2); SB0(); }  \
    if (s_ + 1 < NSTEPS) { PREFETCH(xs1, es1, NAH, NAL, NBH, NBL); }             \
    __builtin_amdgcn_s_setprio(1);                                               \
    MFMA3(CAH, CAL, CBH, CBL);                                                   \
    __builtin_amdgcn_s_setprio(0);                                               \
    if ((s_ & 7) == 7) { EPILOGUE(s_ >> 3); }                                    \
    int tx_ = xs0; xs0 = xs1; xs1 = xs2; xs2 = tx_;                              \
    int te_ = es0; es0 = es1; es1 = es2; es2 = te_;                              \
    } while (0)

    float best[16];
    int bidx[16];
    #pragma unroll
    for (int s = 0; s < 16; ++s) { best[s] = __uint_as_float(0x7f800000u); bidx[s] = 0; }

    f32x4 acc[4][4];
    #pragma unroll
    for (int fi = 0; fi < 4; ++fi)
        #pragma unroll
        for (int fj = 0; fj < 4; ++fj) acc[fi][fj] = (f32x4){0.f, 0.f, 0.f, 0.f};

    bf16x8 aH0[4], aL0[4], bH0[4], bL0[4];
    bf16x8 aH1[4], aL1[4], bH1[4], bL1[4];

    int xs0 = 0, xs1 = XSLOT, xs2 = 2 * XSLOT;
    int es0 = EBASE, es1 = EBASE + ESLOT, es2 = EBASE + 2 * ESLOT;

    // prologue: stage steps 0,1; publish 0; prefetch frags(0) into set0
    stage_X(xs0, 0); stage_E(es0, 0); SB0();
    stage_X(xs1, 1); stage_E(es1, 1); SB0();
    asm volatile("s_waitcnt vmcnt(6)" ::: "memory");
    __builtin_amdgcn_s_barrier();
    PREFETCH(xs0, es0, aH0, aL0, bH0, bL0);

    for (int s2 = 0; s2 < NSTEPS / 2; ++s2) {
        STEP(2 * s2,     aH0, aL0, bH0, bL0, aH1, aL1, bH1, bL1);
        STEP(2 * s2 + 1, aH1, aL1, bH1, bL1, aH0, aL0, bH0, bL0);
    }

    // reduce across the 16 lanes sharing each row; ties -> lowest index
    #pragma unroll
    for (int slot = 0; slot < 16; ++slot) {
        float v = best[slot];
        int ix = bidx[slot];
        #pragma unroll
        for (int off = 1; off < 16; off <<= 1) {
            float v2 = __shfl_xor(v, off);
            int ix2 = __shfl_xor(ix, off);
            if (v2 < v || (v2 == v && ix2 < ix)) { v = v2; ix = ix2; }
        }
        if (lane15 == 0) {
            int fi = slot >> 2, r = slot & 3;
            int row = row0 + wr0 + fi * 16 + l16 * 4 + r;
            uint32_t u = __float_as_uint(v);
            uint32_t ord = (u & 0x80000000u) ? ~u : (u | 0x80000000u);
            partials[(size_t)(slice * 2 + wch) * N_VEC + row] =
                ((unsigned long long)ord << 32) | (unsigned)ix;
        }
    }
}

// ---------------- fused: per-row min over partials + gather + loss + counts
__global__ __launch_bounds__(256) void finish_kernel(
    const float* __restrict__ x, const float* __restrict__ emb,
    const unsigned long long* __restrict__ partials,
    float* __restrict__ out_ind, float* __restrict__ out_q,
    unsigned* __restrict__ counts, float* __restrict__ loss_acc) {
    __shared__ float partial[4];
    const int wave = threadIdx.x >> 6;
    const int lane = threadIdx.x & 63;
    const int row = blockIdx.x * 4 + wave;

    unsigned long long m = ~0ull;
    if (lane < NPART) m = partials[(size_t)lane * N_VEC + row];
    #pragma unroll
    for (int off = 1; off < NPART; off <<= 1) {
        unsigned long long v = __shfl_xor(m, off);
        if (v < m) m = v;
    }
    m = __shfl(m, 0);
    const int ix = (int)(unsigned)(m & 0xFFFFFFFFull);

    float4 q = *(const float4*)(emb + (size_t)ix * DIM + lane * 4);
    float4 xv = *(const float4*)(x + (size_t)row * DIM + lane * 4);
    *(float4*)(out_q + (size_t)row * DIM + lane * 4) = q;
    float dx = q.x - xv.x, dy = q.y - xv.y, dz = q.z - xv.z, dw = q.w - xv.w;
    float s = dx * dx + dy * dy + dz * dz + dw * dw;
    #pragma unroll
    for (int off = 32; off; off >>= 1) s += __shfl_xor(s, off);
    if (lane == 0) {
        out_ind[row] = (float)ix;
        atomicAdd(&counts[ix], 1u);
        partial[wave] = s;
    }
    __syncthreads();
    if (threadIdx.x == 0)
        atomicAdd(loss_acc, partial[0] + partial[1] + partial[2] + partial[3]);
}

// -------------------------------------------------- entropy / loss finalize
__global__ __launch_bounds__(256) void finalize_kernel(
    const unsigned* __restrict__ counts, const float* __restrict__ loss_acc,
    float* __restrict__ out_scalars) {
    __shared__ float red[256];
    float h = 0.0f;
    for (int c = threadIdx.x; c < M_CODES; c += 256) {
        float p = (float)counts[c] * (1.0f / (float)N_VEC);
        h += p * logf(p + 1e-10f);
    }
    red[threadIdx.x] = h;
    __syncthreads();
    for (int s = 128; s; s >>= 1) {
        if (threadIdx.x < s) red[threadIdx.x] += red[threadIdx.x + s];
        __syncthreads();
    }
    if (threadIdx.x == 0) {
        out_scalars[0] = BETA * loss_acc[0] / (float)(N_VEC * DIM);
        out_scalars[1] = expf(-red[0]);
    }
}

extern "C" void kernel_launch(void* const* d_in, const int* in_sizes, int n_in,
                              void* d_out, int out_size, void* d_ws, size_t ws_size,
                              hipStream_t stream) {
    const float* x = (const float*)d_in[0];
    const float* emb = (const float*)d_in[1];

    float* out = (float*)d_out;
    float* out_q = out;                                   // N*DIM
    float* out_ind = out + (size_t)N_VEC * DIM;           // N
    float* out_scalars = out_ind + N_VEC;                 // 2

    // x hi/lo scratch lives in d_out's quantized region (rewritten by finish)
    ushort* xh = (ushort*)out;                            // 8 MB
    ushort* xl = xh + (size_t)N_VEC * DIM;                // 8 MB

    char* wp = (char*)d_ws;
    ushort* eh = (ushort*)wp;  wp += (size_t)M_CODES * DIM * 2;   // 4 MB
    ushort* el = (ushort*)wp;  wp += (size_t)M_CODES * DIM * 2;   // 4 MB
    float* e2 = (float*)wp;    wp += (size_t)M_CODES * 4;         // 32 KB
    unsigned long long* partials = (unsigned long long*)wp;
    wp += (size_t)NPART * N_VEC * 8;                              // 1 MB
    unsigned* counts = (unsigned*)wp; wp += (size_t)M_CODES * 4;  // 32 KB
    float* loss_acc = (float*)wp;                                 // 4 B

    prep_kernel<<<(N_VEC + M_CODES) / 4, 256, 0, stream>>>(x, emb, xh, xl, eh, el,
                                                           e2, counts, loss_acc);

    hipFuncSetAttribute((const void*)vq_mfma_kernel,
                        hipFuncAttributeMaxDynamicSharedMemorySize, LDS_TOTAL);
    vq_mfma_kernel<<<(N_VEC / BM) * NSLICE, 512, LDS_TOTAL, stream>>>(
        xh, xl, eh, el, e2, partials);

    finish_kernel<<<N_VEC / 4, 256, 0, stream>>>(x, emb, partials, out_ind, out_q,
                                                 counts, loss_acc);
    finalize_kernel<<<1, 256, 0, stream>>>(counts, loss_acc, out_scalars);
}

// Round 10
// 261.037 us; speedup vs baseline: 2.3210x; 2.3210x over previous
//
#include <hip/hip_runtime.h>
#include <stdint.h>

// VectorQuantize on MI355X (gfx950) — bf16x3 MFMA distance-GEMM + argmin.
// Round 10: r7 base (BM=256 x BN=128, wave 64x64, X2/E3 counted-vmcnt(2) ring,
// rt-major XCD mapping, e2-in-LDS) + A-frag hoist + 1-ahead B-frag software
// pipeline (named alternating sets) to hide ds_read latency under MFMAs.
// d_out: [0..N*DIM) quantized (fp32), [N*DIM..+N) ind (fp32), loss, perplexity.

#define N_VEC 16384
#define M_CODES 8192
#define DIM 256
#define BETA 0.25f

#define NSLICE 4
#define SLICE_CODES 2048
#define BM 256
#define BN 128
#define NPART 8                  // NSLICE * 2 col halves

#define XSLOT 32768              // xh 16K | xl 16K   (256 rows x 64B)
#define ESLOT 16384              // eh 8K  | el 8K    (128 rows x 64B)
#define EBASE (3 * XSLOT)                    // 98304 (slot layout as r7)
#define E2OFF (EBASE + 3 * ESLOT)            // 147456
#define LDS_TOTAL (E2OFF + SLICE_CODES * 4)  // 155648 = 152 KiB
#define NSTEPS 128               // 16 ct x 8 kc

typedef __attribute__((ext_vector_type(4))) float f32x4;
typedef __attribute__((ext_vector_type(8))) __bf16 bf16x8;

__device__ __forceinline__ void gll16(const void* g, const void* lds_p) {
    __builtin_amdgcn_global_load_lds(
        (const __attribute__((address_space(1))) uint32_t*)(uintptr_t)g,
        (__attribute__((address_space(3))) uint32_t*)(uint32_t)(uintptr_t)lds_p,
        16, 0, 0);
}
#define SB0() __builtin_amdgcn_sched_barrier(0)

__device__ __forceinline__ ushort f2bf(float f) {
    uint32_t u = __float_as_uint(f);
    return (ushort)((u + 0x7FFFu + ((u >> 16) & 1u)) >> 16);  // RNE
}
__device__ __forceinline__ float bf2f(ushort h) {
    return __uint_as_float(((uint32_t)h) << 16);
}

// ---- fused: split fp32 -> bf16 hi/lo for x and e, e2, zero counts/loss ----
__global__ __launch_bounds__(256) void prep_kernel(
    const float* __restrict__ x, const float* __restrict__ emb,
    ushort* __restrict__ xh, ushort* __restrict__ xl,
    ushort* __restrict__ eh, ushort* __restrict__ el,
    float* __restrict__ e2, unsigned* __restrict__ counts,
    float* __restrict__ loss_acc) {
    if (blockIdx.x < 8) {
        int4 z = {0, 0, 0, 0};
        ((int4*)counts)[blockIdx.x * 256 + threadIdx.x] = z;
        if (blockIdx.x == 0 && threadIdx.x == 0) *loss_acc = 0.0f;
    }
    const int wave = threadIdx.x >> 6;
    const int lane = threadIdx.x & 63;
    const int row = blockIdx.x * 4 + wave;

    const float* src;
    ushort* ph;
    ushort* pl;
    bool is_e;
    int er = row - N_VEC;
    if (row < N_VEC) {
        src = x + (size_t)row * DIM;
        ph = xh + (size_t)row * DIM;
        pl = xl + (size_t)row * DIM;
        is_e = false;
    } else {
        src = emb + (size_t)er * DIM;
        ph = eh + (size_t)er * DIM;
        pl = el + (size_t)er * DIM;
        is_e = true;
    }
    float4 v = *(const float4*)(src + lane * 4);
    ushort h0 = f2bf(v.x), h1 = f2bf(v.y), h2 = f2bf(v.z), h3 = f2bf(v.w);
    ushort l0 = f2bf(v.x - bf2f(h0)), l1 = f2bf(v.y - bf2f(h1));
    ushort l2 = f2bf(v.z - bf2f(h2)), l3 = f2bf(v.w - bf2f(h3));
    *(ushort4*)(ph + lane * 4) = make_ushort4(h0, h1, h2, h3);
    *(ushort4*)(pl + lane * 4) = make_ushort4(l0, l1, l2, l3);
    if (is_e) {
        float s = v.x * v.x + v.y * v.y + v.z * v.z + v.w * v.w;
        #pragma unroll
        for (int off = 32; off; off >>= 1) s += __shfl_xor(s, off);
        if (lane == 0) e2[er] = s;
    }
}

// ------ main: bf16x3 MFMA distance GEMM, X2/E3 counted ring, argmin ----
__global__ __launch_bounds__(512, 1) void vq_mfma_kernel(
    const ushort* __restrict__ xh, const ushort* __restrict__ xl,
    const ushort* __restrict__ eh, const ushort* __restrict__ el,
    const float* __restrict__ e2g, unsigned long long* __restrict__ partials) {
    extern __shared__ char lds[];

    const int t = threadIdx.x;
    const int lane = t & 63;
    const int wv = t >> 6;          // 0..7
    const int lane15 = lane & 15;
    const int l16 = lane >> 4;      // 0..3

    // rt-major mapping: XCD = bid%8 = rt%8 -> slice-siblings co-XCD
    const int rt = blockIdx.x & 63;
    const int slice = blockIdx.x >> 6;   // 0..3
    const int row0 = rt * BM;
    const int cslice0 = slice * SLICE_CODES;

    const int wr0 = (wv & 3) * 64;   // wave row quadrant 0..192
    const int wch = wv >> 2;         // wave col half (64 codes)

    // ---- fragment LDS byte bases (swizzle term is f-independent)
    const int swz = ((l16 ^ (lane15 >> 1)) & 3) << 4;
    const int byteA0 = (wr0 + lane15) * 64 + swz;
    const int byteB0 = (wch * 64 + lane15) * 64 + swz;

    // ---- staging: linear LDS dest, inverse-swizzled global source
    const int sX0 = wv * 128 + lane;
    const int sX1 = sX0 + 64;
    const int rX0 = sX0 >> 2, rX1 = sX1 >> 2;
    const int cX0 = ((sX0 & 3) ^ ((sX0 >> 3) & 3)) << 3;
    const int cX1 = ((sX1 & 3) ^ ((sX1 >> 3) & 3)) << 3;
    const int sE = wv * 64 + lane;
    const int rE = sE >> 2;
    const int cE = ((sE & 3) ^ ((sE >> 3) & 3)) << 3;

    const ushort* pxh_a = xh + (size_t)(row0 + rX0) * DIM + cX0;
    const ushort* pxh_b = xh + (size_t)(row0 + rX1) * DIM + cX1;
    const ushort* pxl_a = xl + (size_t)(row0 + rX0) * DIM + cX0;
    const ushort* pxl_b = xl + (size_t)(row0 + rX1) * DIM + cX1;
    const ushort* peh = eh + (size_t)(cslice0 + rE) * DIM + cE;
    const ushort* pel = el + (size_t)(cslice0 + rE) * DIM + cE;

    // ---- preload e2 slice into LDS; syncthreads drains vmcnt FIFO
    float* e2s = (float*)(lds + E2OFF);
    #pragma unroll
    for (int i = 0; i < 4; ++i) e2s[i * 512 + t] = e2g[cslice0 + i * 512 + t];
    __syncthreads();

    auto stage_X = [&](int s) {   // 4 gll
        char* b = lds + (s & 1) * XSLOT + wv * 2048;
        const int xo = (s & 7) * 32;
        gll16(pxh_a + xo, b);
        gll16(pxh_b + xo, b + 1024);
        gll16(pxl_a + xo, b + 16384);
        gll16(pxl_b + xo, b + 16384 + 1024);
    };
    auto stage_E = [&](int slot, int s) {   // 2 gll
        char* b = lds + EBASE + slot * ESLOT + wv * 1024;
        const size_t eo = ((size_t)(s >> 3) << 15) + (s & 7) * 32;  // ct*BN*DIM + kc*32
        gll16(peh + eo, b);
        gll16(pel + eo, b + 8192);
    };

    float best[16];
    int bidx[16];
    #pragma unroll
    for (int s = 0; s < 16; ++s) { best[s] = __uint_as_float(0x7f800000u); bidx[s] = 0; }

    f32x4 acc[4][4];
    #pragma unroll
    for (int fi = 0; fi < 4; ++fi)
        #pragma unroll
        for (int fj = 0; fj < 4; ++fj) acc[fi][fj] = (f32x4){0.f, 0.f, 0.f, 0.f};

    // prologue: X(0), E(0), E(1) in flight (order pinned)
    stage_X(0); SB0();
    stage_E(0, 0); SB0();
    stage_E(1, 1); SB0();

    // 12 MFMAs of one fj column (hh, hl, lh)
#define FJ_MFMA(FJ, BH, BL) do {                                         \
    _Pragma("unroll") for (int fi_ = 0; fi_ < 4; ++fi_)                  \
        acc[fi_][FJ] = __builtin_amdgcn_mfma_f32_16x16x32_bf16(          \
            ah[fi_], BH, acc[fi_][FJ], 0, 0, 0);                         \
    _Pragma("unroll") for (int fi_ = 0; fi_ < 4; ++fi_)                  \
        acc[fi_][FJ] = __builtin_amdgcn_mfma_f32_16x16x32_bf16(          \
            ah[fi_], BL, acc[fi_][FJ], 0, 0, 0);                         \
    _Pragma("unroll") for (int fi_ = 0; fi_ < 4; ++fi_)                  \
        acc[fi_][FJ] = __builtin_amdgcn_mfma_f32_16x16x32_bf16(          \
            alo[fi_], BH, acc[fi_][FJ], 0, 0, 0);                        \
    } while (0)

    int esl = 0;  // E slot of current step = s%3
    for (int s = 0; s < NSTEPS; ++s) {
        // entry FIFO: E(s)[2] oldest, X(s)[4], E(s+1)[2] -> wait leaves 2
        if (s == NSTEPS - 1) {
            asm volatile("s_waitcnt vmcnt(0)" ::: "memory");
        } else {
            asm volatile("s_waitcnt vmcnt(2)" ::: "memory");
        }
        __builtin_amdgcn_s_barrier();
        SB0();
        if (s + 1 < NSTEPS) { stage_X(s + 1); SB0(); }
        const int stslot = (esl >= 1) ? esl - 1 : 2;   // (s+2)%3
        if (s + 2 < NSTEPS) { stage_E(stslot, s + 2); SB0(); }

        const char* lbX = lds + (s & 1) * XSLOT;
        const char* lbE = lds + EBASE + esl * ESLOT;

        // B fj=0 issued first (longest latency), then the 8 A-frag reads.
        bf16x8 bhA = *(const bf16x8*)(lbE + byteB0);
        bf16x8 blA = *(const bf16x8*)(lbE + 8192 + byteB0);
        bf16x8 ah[4], alo[4];
        #pragma unroll
        for (int f = 0; f < 4; ++f) {
            ah[f] = *(const bf16x8*)(lbX + byteA0 + f * 1024);
            alo[f] = *(const bf16x8*)(lbX + 16384 + byteA0 + f * 1024);
        }

        __builtin_amdgcn_s_setprio(1);
        // fj pipeline: read fj+1's pair before fj's 12 MFMAs (alternating sets)
        bf16x8 bhB = *(const bf16x8*)(lbE + byteB0 + 1024);
        bf16x8 blB = *(const bf16x8*)(lbE + 8192 + byteB0 + 1024);
        FJ_MFMA(0, bhA, blA);
        bhA = *(const bf16x8*)(lbE + byteB0 + 2048);
        blA = *(const bf16x8*)(lbE + 8192 + byteB0 + 2048);
        FJ_MFMA(1, bhB, blB);
        bhB = *(const bf16x8*)(lbE + byteB0 + 3072);
        blB = *(const bf16x8*)(lbE + 8192 + byteB0 + 3072);
        FJ_MFMA(2, bhA, blA);
        FJ_MFMA(3, bhB, blB);
        __builtin_amdgcn_s_setprio(0);
        esl = (esl == 2) ? 0 : esl + 1;

        if ((s & 7) == 7) {
            // epilogue for ct = s>>3: score = e2[c] - 2*dot
            // C/D layout: col = lane15, row = l16*4 + r
            const int ct = s >> 3;
            const int cl = ct * BN + wch * 64 + lane15;
            #pragma unroll
            for (int fj = 0; fj < 4; ++fj) {
                const float e2v = e2s[cl + fj * 16];
                const int c = cslice0 + cl + fj * 16;
                #pragma unroll
                for (int fi = 0; fi < 4; ++fi)
                    #pragma unroll
                    for (int r = 0; r < 4; ++r) {
                        float sc = e2v - 2.0f * acc[fi][fj][r];
                        const int slot = fi * 4 + r;
                        if (sc < best[slot]) { best[slot] = sc; bidx[slot] = c; }
                    }
            }
            #pragma unroll
            for (int fi = 0; fi < 4; ++fi)
                #pragma unroll
                for (int fj = 0; fj < 4; ++fj)
                    acc[fi][fj] = (f32x4){0.f, 0.f, 0.f, 0.f};
        }
    }
#undef FJ_MFMA

    // reduce across the 16 lanes sharing each row; ties -> lowest index
    #pragma unroll
    for (int slot = 0; slot < 16; ++slot) {
        float v = best[slot];
        int ix = bidx[slot];
        #pragma unroll
        for (int off = 1; off < 16; off <<= 1) {
            float v2 = __shfl_xor(v, off);
            int ix2 = __shfl_xor(ix, off);
            if (v2 < v || (v2 == v && ix2 < ix)) { v = v2; ix = ix2; }
        }
        if (lane15 == 0) {
            int fi = slot >> 2, r = slot & 3;
            int row = row0 + wr0 + fi * 16 + l16 * 4 + r;
            uint32_t u = __float_as_uint(v);
            uint32_t ord = (u & 0x80000000u) ? ~u : (u | 0x80000000u);
            partials[(size_t)(slice * 2 + wch) * N_VEC + row] =
                ((unsigned long long)ord << 32) | (unsigned)ix;
        }
    }
}

// ---------------- fused: per-row min over partials + gather + loss + counts
__global__ __launch_bounds__(256) void finish_kernel(
    const float* __restrict__ x, const float* __restrict__ emb,
    const unsigned long long* __restrict__ partials,
    float* __restrict__ out_ind, float* __restrict__ out_q,
    unsigned* __restrict__ counts, float* __restrict__ loss_acc) {
    __shared__ float partial[4];
    const int wave = threadIdx.x >> 6;
    const int lane = threadIdx.x & 63;
    const int row = blockIdx.x * 4 + wave;

    unsigned long long m = ~0ull;
    if (lane < NPART) m = partials[(size_t)lane * N_VEC + row];
    #pragma unroll
    for (int off = 1; off < NPART; off <<= 1) {
        unsigned long long v = __shfl_xor(m, off);
        if (v < m) m = v;
    }
    m = __shfl(m, 0);
    const int ix = (int)(unsigned)(m & 0xFFFFFFFFull);

    float4 q = *(const float4*)(emb + (size_t)ix * DIM + lane * 4);
    float4 xv = *(const float4*)(x + (size_t)row * DIM + lane * 4);
    *(float4*)(out_q + (size_t)row * DIM + lane * 4) = q;
    float dx = q.x - xv.x, dy = q.y - xv.y, dz = q.z - xv.z, dw = q.w - xv.w;
    float s = dx * dx + dy * dy + dz * dz + dw * dw;
    #pragma unroll
    for (int off = 32; off; off >>= 1) s += __shfl_xor(s, off);
    if (lane == 0) {
        out_ind[row] = (float)ix;
        atomicAdd(&counts[ix], 1u);
        partial[wave] = s;
    }
    __syncthreads();
    if (threadIdx.x == 0)
        atomicAdd(loss_acc, partial[0] + partial[1] + partial[2] + partial[3]);
}

// -------------------------------------------------- entropy / loss finalize
__global__ __launch_bounds__(256) void finalize_kernel(
    const unsigned* __restrict__ counts, const float* __restrict__ loss_acc,
    float* __restrict__ out_scalars) {
    __shared__ float red[256];
    float h = 0.0f;
    for (int c = threadIdx.x; c < M_CODES; c += 256) {
        float p = (float)counts[c] * (1.0f / (float)N_VEC);
        h += p * logf(p + 1e-10f);
    }
    red[threadIdx.x] = h;
    __syncthreads();
    for (int s = 128; s; s >>= 1) {
        if (threadIdx.x < s) red[threadIdx.x] += red[threadIdx.x + s];
        __syncthreads();
    }
    if (threadIdx.x == 0) {
        out_scalars[0] = BETA * loss_acc[0] / (float)(N_VEC * DIM);
        out_scalars[1] = expf(-red[0]);
    }
}

extern "C" void kernel_launch(void* const* d_in, const int* in_sizes, int n_in,
                              void* d_out, int out_size, void* d_ws, size_t ws_size,
                              hipStream_t stream) {
    const float* x = (const float*)d_in[0];
    const float* emb = (const float*)d_in[1];

    float* out = (float*)d_out;
    float* out_q = out;                                   // N*DIM
    float* out_ind = out + (size_t)N_VEC * DIM;           // N
    float* out_scalars = out_ind + N_VEC;                 // 2

    // x hi/lo scratch lives in d_out's quantized region (rewritten by finish)
    ushort* xh = (ushort*)out;                            // 8 MB
    ushort* xl = xh + (size_t)N_VEC * DIM;                // 8 MB

    char* wp = (char*)d_ws;
    ushort* eh = (ushort*)wp;  wp += (size_t)M_CODES * DIM * 2;   // 4 MB
    ushort* el = (ushort*)wp;  wp += (size_t)M_CODES * DIM * 2;   // 4 MB
    float* e2 = (float*)wp;    wp += (size_t)M_CODES * 4;         // 32 KB
    unsigned long long* partials = (unsigned long long*)wp;
    wp += (size_t)NPART * N_VEC * 8;                              // 1 MB
    unsigned* counts = (unsigned*)wp; wp += (size_t)M_CODES * 4;  // 32 KB
    float* loss_acc = (float*)wp;                                 // 4 B

    prep_kernel<<<(N_VEC + M_CODES) / 4, 256, 0, stream>>>(x, emb, xh, xl, eh, el,
                                                           e2, counts, loss_acc);

    hipFuncSetAttribute((const void*)vq_mfma_kernel,
                        hipFuncAttributeMaxDynamicSharedMemorySize, LDS_TOTAL);
    vq_mfma_kernel<<<(N_VEC / BM) * NSLICE, 512, LDS_TOTAL, stream>>>(
        xh, xl, eh, el, e2, partials);

    finish_kernel<<<N_VEC / 4, 256, 0, stream>>>(x, emb, partials, out_ind, out_q,
                                                 counts, loss_acc);
    finalize_kernel<<<1, 256, 0, stream>>>(counts, loss_acc, out_scalars);
}